// Round 18
// baseline (444.723 us; speedup 1.0000x reference)
//
#include <hip/hip_runtime.h>
#include <hip/hip_bf16.h>

#define HDIM 512
#define TILE 64
#define TPB 512

typedef __attribute__((ext_vector_type(8))) short short8;
typedef __attribute__((ext_vector_type(4))) short s16x4;
typedef __attribute__((ext_vector_type(4))) float f32x4;
typedef __attribute__((ext_vector_type(16))) float f32x16;

__device__ __forceinline__ unsigned short f2bf(float x) {
  __hip_bfloat16 h = __float2bfloat16(x);
  return *reinterpret_cast<unsigned short*>(&h);
}
__device__ __forceinline__ float bf2f(unsigned short h) {
  return __uint_as_float(((unsigned)h) << 16);
}
__device__ __forceinline__ float fsig(float z) {
  return __builtin_amdgcn_rcpf(1.f + __expf(-z));
}
// bufA is [e][n] (TILE x 512 bf16), XOR swizzle on elem bits 3-6.
__device__ __forceinline__ int bidx(int e, int n) {
  return e * HDIM + (n ^ ((e & 15) << 3));
}

// W2 -> 32x32x16 A-fragment-major: frag[nb16][kc32][lane][j];
// A[m=n][k]: n = nb*32+(l&31), k = kc*16+(l>>5)*8+j.
__global__ void prep_weights(const float* __restrict__ pW2, const float* __restrict__ tW2,
                             unsigned short* __restrict__ pWf, unsigned short* __restrict__ pWb,
                             unsigned short* __restrict__ tWf, unsigned short* __restrict__ tWb) {
  int i = blockIdx.x * blockDim.x + threadIdx.x;
  if (i >= HDIM * HDIM) return;
  int j  = i & 7;
  int l  = (i >> 3) & 63;
  int kc = (i >> 9) & 31;
  int nb = i >> 14;
  int npos = nb * 32 + (l & 31);
  int kpos = kc * 16 + ((l >> 5) << 3) + j;
  pWf[i] = f2bf(pW2[kpos * HDIM + npos]);   // fwd: A = W2[k][n]
  pWb[i] = f2bf(pW2[npos * HDIM + kpos]);   // bwd: A = W2[n'][k]
  tWf[i] = f2bf(tW2[kpos * HDIM + npos]);
  tWb[i] = f2bf(tW2[npos * HDIM + kpos]);
}

// W1 -> layer-1 32x32x16 A-frags (hi/lo split, K=16 zero-padded past IN):
// frag[nb16][lane][j]; and phase-5 A-frags frag[kc32][lane][j].
__global__ void prep_w1(const float* __restrict__ W1, int IN, int GD,
                        unsigned short* __restrict__ hi, unsigned short* __restrict__ lo,
                        unsigned short* __restrict__ p5) {
  int i = blockIdx.x * blockDim.x + threadIdx.x;
  if (i < 16 * 64 * 8) {
    int j = i & 7, l = (i >> 3) & 63, nb = i >> 9;
    int k = ((l >> 5) << 3) + j;
    int col = nb * 32 + (l & 31);
    float v = (k < IN) ? W1[k * HDIM + col] : 0.f;
    unsigned short h = f2bf(v);
    hi[i] = h;
    lo[i] = f2bf(v - bf2f(h));
  } else if (i < 16 * 64 * 8 + 32 * 64 * 8) {
    int i2 = i - 16 * 64 * 8;
    int j = i2 & 7, l = (i2 >> 3) & 63, kc = i2 >> 9;
    int g = l & 31;
    int n = kc * 16 + ((l >> 5) << 3) + j;
    p5[i2] = f2bf((g < GD) ? W1[g * HDIM + n] : 0.f);
  }
}

// One merged kernel: blocks [0,nb2) pair edges, rest triples. 32x32x16 MFMA,
// depth-2 register-ring weight prefetch in the GEMM phases.
__global__ void __launch_bounds__(TPB, 2)   // VGPR clamp 128 (empirical 256/w)
energy_kernel(const float* __restrict__ x, const float* __restrict__ sigp,
              const int* __restrict__ ep, const int* __restrict__ et,
              int E2, int E3, int nb2,
              const unsigned short* __restrict__ pW1hi, const unsigned short* __restrict__ pW1lo,
              const unsigned short* __restrict__ pW1p5,
              const unsigned short* __restrict__ tW1hi, const unsigned short* __restrict__ tW1lo,
              const unsigned short* __restrict__ tW1p5,
              const float* __restrict__ pb1, const float* __restrict__ tb1,
              const unsigned short* __restrict__ pWf, const unsigned short* __restrict__ pWb,
              const unsigned short* __restrict__ tWf, const unsigned short* __restrict__ tWb,
              const float* __restrict__ pb2, const float* __restrict__ tb2,
              const float* __restrict__ pw3, const float* __restrict__ tw3,
              const float* __restrict__ pb3, const float* __restrict__ tb3,
              float* __restrict__ out) {
  __shared__ __align__(16) unsigned short bufA[TILE * HDIM];  // h1 -> dz2 -> dz1 (64 KB)
  __shared__ __align__(16) float h0s[TILE][16];
  __shared__ float dh0sT[8][TILE];
  __shared__ int   idxs[TILE * 3];
  __shared__ float blockE;

  const bool isP = (int)blockIdx.x < nb2;
  const int arity = isP ? 2 : 3;
  const int GD = 2 * arity;
  const int Etot = isP ? E2 : E3;
  const int* __restrict__ edges = isP ? ep : et;
  const unsigned short* __restrict__ W1hi = isP ? pW1hi : tW1hi;
  const unsigned short* __restrict__ W1lo = isP ? pW1lo : tW1lo;
  const unsigned short* __restrict__ W1p5 = isP ? pW1p5 : tW1p5;
  const unsigned short* __restrict__ Wf = isP ? pWf : tWf;
  const unsigned short* __restrict__ Wb = isP ? pWb : tWb;
  const float* __restrict__ b1 = isP ? pb1 : tb1;
  const float* __restrict__ b2 = isP ? pb2 : tb2;
  const float* __restrict__ w3 = isP ? pw3 : tw3;
  const float* __restrict__ b3p = isP ? pb3 : tb3;

  const int tid  = threadIdx.x;
  const int lane = tid & 63;
  const int w    = tid >> 6;            // 8 waves; wave owns n-cols [w*64, w*64+64)
  const int l31  = lane & 31;
  const int lh   = lane >> 5;
  const int tile0 = (isP ? (int)blockIdx.x : (int)blockIdx.x - nb2) * TILE;
  const int vcnt  = min(TILE, Etot - tile0);
  const float sigma = sigp[0];

  // ---- phase 0: init ----
  if (tid == 0) blockE = 0.f;
  ((float*)dh0sT)[tid] = 0.f;
  if (tid < TILE * arity) {
    int e = tid / arity;
    idxs[tid] = (e < vcnt) ? edges[(size_t)tile0 * arity + tid] : 0;
  }
  __syncthreads();
  if (tid < TILE) {
#pragma unroll
    for (int k = 0; k < 16; ++k) h0s[tid][k] = 0.f;
    if (tid < vcnt) {
      for (int o = 0; o < arity; ++o) {
        int id = idxs[tid * arity + o];
        h0s[tid][o * 2 + 0] = x[id * 2 + 0];
        h0s[tid][o * 2 + 1] = x[id * 2 + 1];
        h0s[tid][arity * 2 + o] = sigma;
      }
    }
  }
  __syncthreads();

  const int n0 = w * 64;

  f32x16 acc[2][2];    // [nb][eb], C: col(e)=l31, row(n)=(r&3)+8*(r>>2)+4*lh
#pragma unroll
  for (int nb = 0; nb < 2; ++nb)
#pragma unroll
    for (int eb = 0; eb < 2; ++eb)
#pragma unroll
      for (int r = 0; r < 16; ++r) acc[nb][eb][r] = 0.f;

  // ---- phase 1: z1^T = W1^T h0^T (split-bf16, single K=16 step) ----
  {
    short8 Hh[2], Hl[2];
#pragma unroll
    for (int eb = 0; eb < 2; ++eb) {
      const float* p = &h0s[eb * 32 + l31][lh * 8];
      f32x4 v0 = *(const f32x4*)p;
      f32x4 v1 = *(const f32x4*)(p + 4);
#pragma unroll
      for (int j = 0; j < 4; ++j) {
        unsigned short ha = f2bf(v0[j]);
        Hh[eb][j] = (short)ha;
        Hl[eb][j] = (short)f2bf(v0[j] - bf2f(ha));
        unsigned short hb_ = f2bf(v1[j]);
        Hh[eb][j + 4] = (short)hb_;
        Hl[eb][j + 4] = (short)f2bf(v1[j] - bf2f(hb_));
      }
    }
#pragma unroll
    for (int nb = 0; nb < 2; ++nb) {
      int nbg = w * 2 + nb;
      short8 A1h = *(const short8*)(W1hi + ((nbg * 64 + lane) << 3));
      short8 A1l = *(const short8*)(W1lo + ((nbg * 64 + lane) << 3));
#pragma unroll
      for (int eb = 0; eb < 2; ++eb) {
        acc[nb][eb] = __builtin_amdgcn_mfma_f32_32x32x16_bf16(A1h, Hh[eb], acc[nb][eb], 0, 0, 0);
        acc[nb][eb] = __builtin_amdgcn_mfma_f32_32x32x16_bf16(A1l, Hh[eb], acc[nb][eb], 0, 0, 0);
        acc[nb][eb] = __builtin_amdgcn_mfma_f32_32x32x16_bf16(A1h, Hl[eb], acc[nb][eb], 0, 0, 0);
      }
    }
  }
  // silu(z1) -> bufA[e][n], b64 per 4-reg group
#pragma unroll
  for (int nb = 0; nb < 2; ++nb) {
    int nbase = n0 + nb * 32;
#pragma unroll
    for (int eb = 0; eb < 2; ++eb) {
      int e = eb * 32 + l31;
      bool val = e < vcnt;
#pragma unroll
      for (int g = 0; g < 4; ++g) {
        int n4 = nbase + 8 * g + 4 * lh;
        f32x4 b1x = *(const f32x4*)&b1[n4];
        s16x4 pk;
#pragma unroll
        for (int r = 0; r < 4; ++r) {
          float z = acc[nb][eb][4 * g + r] + b1x[r];
          float s = fsig(z);
          pk[r] = (short)f2bf(val ? z * s : 0.f);
        }
        *(s16x4*)&bufA[bidx(e, n4)] = pk;
      }
    }
  }
  __syncthreads();

  // ---- phase 2: z2^T = W2^T h1^T, depth-2 af ring + setprio ----
#pragma unroll
  for (int nb = 0; nb < 2; ++nb)
#pragma unroll
    for (int eb = 0; eb < 2; ++eb)
#pragma unroll
      for (int r = 0; r < 16; ++r) acc[nb][eb][r] = 0.f;

  {
    short8 afb[2][2][2];   // [slot][nb][t] depth-2 ring
#pragma unroll
    for (int s = 0; s < 2; ++s)
#pragma unroll
      for (int nb = 0; nb < 2; ++nb)
#pragma unroll
        for (int t = 0; t < 2; ++t)
          afb[s][nb][t] = *(const short8*)(Wf + ((((w * 2 + nb) * 32 + s * 2 + t) * 64 + lane) << 3));
#pragma unroll
    for (int c = 0; c < 16; ++c) {
      short8 hb[2][2];     // [eb][t]
#pragma unroll
      for (int eb = 0; eb < 2; ++eb)
#pragma unroll
        for (int t = 0; t < 2; ++t)
          hb[eb][t] = *(const short8*)&bufA[bidx(eb * 32 + l31, (c * 2 + t) * 16 + lh * 8)];
      __builtin_amdgcn_s_setprio(1);
#pragma unroll
      for (int t = 0; t < 2; ++t)
#pragma unroll
        for (int nb = 0; nb < 2; ++nb)
#pragma unroll
          for (int eb = 0; eb < 2; ++eb)
            acc[nb][eb] = __builtin_amdgcn_mfma_f32_32x32x16_bf16(afb[c & 1][nb][t], hb[eb][t], acc[nb][eb], 0, 0, 0);
      __builtin_amdgcn_s_setprio(0);
      int cn = (c + 2) & 15;   // branchless wrap; c=14,15 reload c=0,1 (unused)
#pragma unroll
      for (int nb = 0; nb < 2; ++nb)
#pragma unroll
        for (int t = 0; t < 2; ++t)
          afb[c & 1][nb][t] = *(const short8*)(Wf + ((((w * 2 + nb) * 32 + cn * 2 + t) * 64 + lane) << 3));
    }
  }

  // ---- epilogue fwd: energy + dz2 = w3*silu'(z2) ----
  float epart = 0.f;
#pragma unroll
  for (int nb = 0; nb < 2; ++nb) {
    int nbase = n0 + nb * 32;
#pragma unroll
    for (int eb = 0; eb < 2; ++eb) {
      bool val = (eb * 32 + l31) < vcnt;
#pragma unroll
      for (int g = 0; g < 4; ++g) {
        int n4 = nbase + 8 * g + 4 * lh;
        f32x4 b2x = *(const f32x4*)&b2[n4];
        f32x4 w3x = *(const f32x4*)&w3[n4];
#pragma unroll
        for (int r = 0; r < 4; ++r) {
          float z = acc[nb][eb][4 * g + r] + b2x[r];
          float s = fsig(z);
          float h2 = z * s;
          float sp = s * (1.f + z * (1.f - s));
          epart += val ? h2 * w3x[r] : 0.f;
          acc[nb][eb][4 * g + r] = val ? w3x[r] * sp : 0.f;
        }
      }
    }
  }

  __syncthreads();  // all reads of h1 done
#pragma unroll
  for (int nb = 0; nb < 2; ++nb) {
    int nbase = n0 + nb * 32;
#pragma unroll
    for (int eb = 0; eb < 2; ++eb) {
      int e = eb * 32 + l31;
#pragma unroll
      for (int g = 0; g < 4; ++g) {
        s16x4 pk;
#pragma unroll
        for (int r = 0; r < 4; ++r) pk[r] = (short)f2bf(acc[nb][eb][4 * g + r]);
        *(s16x4*)&bufA[bidx(e, nbase + 8 * g + 4 * lh)] = pk;
      }
    }
  }
#pragma unroll
  for (int off = 32; off > 0; off >>= 1) epart += __shfl_down(epart, off, 64);
  if (lane == 0) atomicAdd(&blockE, epart);
  __syncthreads();
  if (tid == 0) atomicAdd(out, blockE + (float)vcnt * b3p[0]);

  // ---- phase 3: dH1^T = W2 dz2^T, depth-2 af ring + setprio ----
#pragma unroll
  for (int nb = 0; nb < 2; ++nb)
#pragma unroll
    for (int eb = 0; eb < 2; ++eb)
#pragma unroll
      for (int r = 0; r < 16; ++r) acc[nb][eb][r] = 0.f;

  {
    short8 afb[2][2][2];
#pragma unroll
    for (int s = 0; s < 2; ++s)
#pragma unroll
      for (int nb = 0; nb < 2; ++nb)
#pragma unroll
        for (int t = 0; t < 2; ++t)
          afb[s][nb][t] = *(const short8*)(Wb + ((((w * 2 + nb) * 32 + s * 2 + t) * 64 + lane) << 3));
#pragma unroll
    for (int c = 0; c < 16; ++c) {
      short8 hb[2][2];
#pragma unroll
      for (int eb = 0; eb < 2; ++eb)
#pragma unroll
        for (int t = 0; t < 2; ++t)
          hb[eb][t] = *(const short8*)&bufA[bidx(eb * 32 + l31, (c * 2 + t) * 16 + lh * 8)];
      __builtin_amdgcn_s_setprio(1);
#pragma unroll
      for (int t = 0; t < 2; ++t)
#pragma unroll
        for (int nb = 0; nb < 2; ++nb)
#pragma unroll
          for (int eb = 0; eb < 2; ++eb)
            acc[nb][eb] = __builtin_amdgcn_mfma_f32_32x32x16_bf16(afb[c & 1][nb][t], hb[eb][t], acc[nb][eb], 0, 0, 0);
      __builtin_amdgcn_s_setprio(0);
      int cn = (c + 2) & 15;
#pragma unroll
      for (int nb = 0; nb < 2; ++nb)
#pragma unroll
        for (int t = 0; t < 2; ++t)
          afb[c & 1][nb][t] = *(const short8*)(Wb + ((((w * 2 + nb) * 32 + cn * 2 + t) * 64 + lane) << 3));
    }
  }

  // ---- phase 4: dz1 = dH1 * silu'(z1); z1 via bf16 re-MFMA (Hh rebuilt) ----
#pragma unroll
  for (int nb = 0; nb < 2; ++nb) {
    int nbg = w * 2 + nb;
    int nbase = n0 + nb * 32;
    short8 A1h = *(const short8*)(W1hi + ((nbg * 64 + lane) << 3));
#pragma unroll
    for (int eb = 0; eb < 2; ++eb) {
      short8 Hh;
      {
        const float* p = &h0s[eb * 32 + l31][lh * 8];
        f32x4 v0 = *(const f32x4*)p;
        f32x4 v1 = *(const f32x4*)(p + 4);
#pragma unroll
        for (int j = 0; j < 4; ++j) {
          Hh[j] = (short)f2bf(v0[j]);
          Hh[j + 4] = (short)f2bf(v1[j]);
        }
      }
      f32x16 zacc;
#pragma unroll
      for (int r = 0; r < 16; ++r) zacc[r] = 0.f;
      zacc = __builtin_amdgcn_mfma_f32_32x32x16_bf16(A1h, Hh, zacc, 0, 0, 0);
#pragma unroll
      for (int g = 0; g < 4; ++g) {
        f32x4 b1x = *(const f32x4*)&b1[nbase + 8 * g + 4 * lh];
#pragma unroll
        for (int r = 0; r < 4; ++r) {
          float z = zacc[4 * g + r] + b1x[r];
          float s = fsig(z);
          float sp = s * (1.f + z * (1.f - s));
          acc[nb][eb][4 * g + r] *= sp;
        }
      }
    }
  }
  __syncthreads();  // all reads of dz2 done
#pragma unroll
  for (int nb = 0; nb < 2; ++nb) {
    int nbase = n0 + nb * 32;
#pragma unroll
    for (int eb = 0; eb < 2; ++eb) {
      int e = eb * 32 + l31;
#pragma unroll
      for (int g = 0; g < 4; ++g) {
        s16x4 pk;
#pragma unroll
        for (int r = 0; r < 4; ++r) pk[r] = (short)f2bf(acc[nb][eb][4 * g + r]);
        *(s16x4*)&bufA[bidx(e, nbase + 8 * g + 4 * lh)] = pk;
      }
    }
  }
  __syncthreads();

  // ---- phase 5: dh0^T = W1 dz1^T, K(n) split across 8 waves (4 kc each) ----
  {
    f32x16 pacc[2];
#pragma unroll
    for (int eb = 0; eb < 2; ++eb)
#pragma unroll
      for (int r = 0; r < 16; ++r) pacc[eb][r] = 0.f;
#pragma unroll
    for (int t = 0; t < 4; ++t) {
      int kc = w * 4 + t;
      short8 a5 = *(const short8*)(W1p5 + ((kc * 64 + lane) << 3));
#pragma unroll
      for (int eb = 0; eb < 2; ++eb) {
        short8 db = *(const short8*)&bufA[bidx(eb * 32 + l31, kc * 16 + lh * 8)];
        pacc[eb] = __builtin_amdgcn_mfma_f32_32x32x16_bf16(a5, db, pacc[eb], 0, 0, 0);
      }
    }
#pragma unroll
    for (int eb = 0; eb < 2; ++eb)
#pragma unroll
      for (int r = 0; r < 4; ++r) {
        int g = r + 4 * lh;
        if (g < GD) atomicAdd(&dh0sT[g][eb * 32 + l31], pacc[eb][r]);
      }
  }
  __syncthreads();

  // ---- scatter grads ----
  {
    int e = tid & 63, g = tid >> 6;     // 512 threads = 64 edges x 8 comps
    if (e < vcnt && g < GD) {
      int obj = g >> 1, d = g & 1;
      atomicAdd(&out[1 + idxs[e * arity + obj] * 2 + d], dh0sT[g][e]);
    }
  }
}

extern "C" void kernel_launch(void* const* d_in, const int* in_sizes, int n_in,
                              void* d_out, int out_size, void* d_ws, size_t ws_size,
                              hipStream_t stream) {
  const float* x    = (const float*)d_in[0];
  const float* sig  = (const float*)d_in[1];
  const int*   ep   = (const int*)d_in[2];
  const int*   et   = (const int*)d_in[3];
  const float* pW1  = (const float*)d_in[4];
  const float* pb1  = (const float*)d_in[5];
  const float* pW2  = (const float*)d_in[6];
  const float* pb2  = (const float*)d_in[7];
  const float* pW3  = (const float*)d_in[8];
  const float* pb3  = (const float*)d_in[9];
  const float* tW1  = (const float*)d_in[10];
  const float* tb1  = (const float*)d_in[11];
  const float* tW2  = (const float*)d_in[12];
  const float* tb2  = (const float*)d_in[13];
  const float* tW3  = (const float*)d_in[14];
  const float* tb3  = (const float*)d_in[15];
  const int E2 = in_sizes[2] / 2;
  const int E3 = in_sizes[3] / 3;
  float* out = (float*)d_out;

  unsigned short* pWf = (unsigned short*)d_ws;
  unsigned short* pWb = pWf + HDIM * HDIM;
  unsigned short* tWf = pWb + HDIM * HDIM;
  unsigned short* tWb = tWf + HDIM * HDIM;
  unsigned short* pW1hi = tWb + HDIM * HDIM;
  unsigned short* pW1lo = pW1hi + 16 * 64 * 8;
  unsigned short* pW1p5 = pW1lo + 16 * 64 * 8;
  unsigned short* tW1hi = pW1p5 + 32 * 64 * 8;
  unsigned short* tW1lo = tW1hi + 16 * 64 * 8;
  unsigned short* tW1p5 = tW1lo + 16 * 64 * 8;

  const int nb2 = (E2 + TILE - 1) / TILE;
  const int nb3 = (E3 + TILE - 1) / TILE;

  hipMemsetAsync(d_out, 0, (size_t)out_size * sizeof(float), stream);
  prep_weights<<<(HDIM * HDIM + 255) / 256, 256, 0, stream>>>(pW2, tW2, pWf, pWb, tWf, tWb);
  prep_w1<<<(16 * 64 * 8 + 32 * 64 * 8 + 255) / 256, 256, 0, stream>>>(pW1, 6, 4, pW1hi, pW1lo, pW1p5);
  prep_w1<<<(16 * 64 * 8 + 32 * 64 * 8 + 255) / 256, 256, 0, stream>>>(tW1, 9, 6, tW1hi, tW1lo, tW1p5);
  energy_kernel<<<nb2 + nb3, TPB, 0, stream>>>(
      x, sig, ep, et, E2, E3, nb2,
      pW1hi, pW1lo, pW1p5, tW1hi, tW1lo, tW1p5, pb1, tb1,
      pWf, pWb, tWf, tWb, pb2, tb2, pW3, tW3, pb3, tb3, out);
}

// Round 19
// 425.253 us; speedup vs baseline: 1.0458x; 1.0458x over previous
//
#include <hip/hip_runtime.h>
#include <hip/hip_bf16.h>

#define HDIM 512
#define TILE 64
#define TPB 512

typedef __attribute__((ext_vector_type(8))) short short8;
typedef __attribute__((ext_vector_type(4))) short s16x4;
typedef __attribute__((ext_vector_type(4))) float f32x4;
typedef __attribute__((ext_vector_type(16))) float f32x16;

__device__ __forceinline__ unsigned short f2bf(float x) {
  __hip_bfloat16 h = __float2bfloat16(x);
  return *reinterpret_cast<unsigned short*>(&h);
}
__device__ __forceinline__ float bf2f(unsigned short h) {
  return __uint_as_float(((unsigned)h) << 16);
}
__device__ __forceinline__ float fsig(float z) {
  return __builtin_amdgcn_rcpf(1.f + __expf(-z));
}
// bufA is [e][n] (TILE x 512 bf16), XOR swizzle on elem bits 3-6.
__device__ __forceinline__ int bidx(int e, int n) {
  return e * HDIM + (n ^ ((e & 15) << 3));
}

// W2 -> 32x32x16 A-fragment-major: frag[nb16][kc32][lane][j];
// A[m=n][k]: n = nb*32+(l&31), k = kc*16+(l>>5)*8+j.
__global__ void prep_weights(const float* __restrict__ pW2, const float* __restrict__ tW2,
                             unsigned short* __restrict__ pWf, unsigned short* __restrict__ pWb,
                             unsigned short* __restrict__ tWf, unsigned short* __restrict__ tWb) {
  int i = blockIdx.x * blockDim.x + threadIdx.x;
  if (i >= HDIM * HDIM) return;
  int j  = i & 7;
  int l  = (i >> 3) & 63;
  int kc = (i >> 9) & 31;
  int nb = i >> 14;
  int npos = nb * 32 + (l & 31);
  int kpos = kc * 16 + ((l >> 5) << 3) + j;
  pWf[i] = f2bf(pW2[kpos * HDIM + npos]);   // fwd: A = W2[k][n]
  pWb[i] = f2bf(pW2[npos * HDIM + kpos]);   // bwd: A = W2[n'][k]
  tWf[i] = f2bf(tW2[kpos * HDIM + npos]);
  tWb[i] = f2bf(tW2[npos * HDIM + kpos]);
}

// W1 -> layer-1 32x32x16 A-frags (hi/lo split, K=16 zero-padded past IN):
// frag[nb16][lane][j]; and phase-5 A-frags frag[kc32][lane][j].
__global__ void prep_w1(const float* __restrict__ W1, int IN, int GD,
                        unsigned short* __restrict__ hi, unsigned short* __restrict__ lo,
                        unsigned short* __restrict__ p5) {
  int i = blockIdx.x * blockDim.x + threadIdx.x;
  if (i < 16 * 64 * 8) {
    int j = i & 7, l = (i >> 3) & 63, nb = i >> 9;
    int k = ((l >> 5) << 3) + j;
    int col = nb * 32 + (l & 31);
    float v = (k < IN) ? W1[k * HDIM + col] : 0.f;
    unsigned short h = f2bf(v);
    hi[i] = h;
    lo[i] = f2bf(v - bf2f(h));
  } else if (i < 16 * 64 * 8 + 32 * 64 * 8) {
    int i2 = i - 16 * 64 * 8;
    int j = i2 & 7, l = (i2 >> 3) & 63, kc = i2 >> 9;
    int g = l & 31;
    int n = kc * 16 + ((l >> 5) << 3) + j;
    p5[i2] = f2bf((g < GD) ? W1[g * HDIM + n] : 0.f);
  }
}

// One merged kernel: blocks [0,nb2) pair edges, rest triples. 32x32x16 MFMA,
// depth-1 weight prefetch, fused phase4->5 via permlane32_swap (7 barriers).
__global__ void __launch_bounds__(TPB, 2)   // VGPR clamp 128 (empirical 256/w)
energy_kernel(const float* __restrict__ x, const float* __restrict__ sigp,
              const int* __restrict__ ep, const int* __restrict__ et,
              int E2, int E3, int nb2,
              const unsigned short* __restrict__ pW1hi, const unsigned short* __restrict__ pW1lo,
              const unsigned short* __restrict__ pW1p5,
              const unsigned short* __restrict__ tW1hi, const unsigned short* __restrict__ tW1lo,
              const unsigned short* __restrict__ tW1p5,
              const float* __restrict__ pb1, const float* __restrict__ tb1,
              const unsigned short* __restrict__ pWf, const unsigned short* __restrict__ pWb,
              const unsigned short* __restrict__ tWf, const unsigned short* __restrict__ tWb,
              const float* __restrict__ pb2, const float* __restrict__ tb2,
              const float* __restrict__ pw3, const float* __restrict__ tw3,
              const float* __restrict__ pb3, const float* __restrict__ tb3,
              float* __restrict__ out) {
  __shared__ __align__(16) unsigned short bufA[TILE * HDIM];  // h1 -> dz2 (64 KB)
  __shared__ __align__(16) float h0s[TILE][16];
  __shared__ float dh0sT[8][TILE];
  __shared__ int   idxs[TILE * 3];
  __shared__ float blockE;

  const bool isP = (int)blockIdx.x < nb2;
  const int arity = isP ? 2 : 3;
  const int GD = 2 * arity;
  const int Etot = isP ? E2 : E3;
  const int* __restrict__ edges = isP ? ep : et;
  const unsigned short* __restrict__ W1hi = isP ? pW1hi : tW1hi;
  const unsigned short* __restrict__ W1lo = isP ? pW1lo : tW1lo;
  const unsigned short* __restrict__ W1p5 = isP ? pW1p5 : tW1p5;
  const unsigned short* __restrict__ Wf = isP ? pWf : tWf;
  const unsigned short* __restrict__ Wb = isP ? pWb : tWb;
  const float* __restrict__ b1 = isP ? pb1 : tb1;
  const float* __restrict__ b2 = isP ? pb2 : tb2;
  const float* __restrict__ w3 = isP ? pw3 : tw3;
  const float* __restrict__ b3p = isP ? pb3 : tb3;

  const int tid  = threadIdx.x;
  const int lane = tid & 63;
  const int w    = tid >> 6;            // 8 waves; wave owns n-cols [w*64, w*64+64)
  const int l31  = lane & 31;
  const int lh   = lane >> 5;
  const int tile0 = (isP ? (int)blockIdx.x : (int)blockIdx.x - nb2) * TILE;
  const int vcnt  = min(TILE, Etot - tile0);
  const float sigma = sigp[0];

  // ---- phase 0: init ----
  if (tid == 0) blockE = 0.f;
  ((float*)dh0sT)[tid] = 0.f;
  if (tid < TILE * arity) {
    int e = tid / arity;
    idxs[tid] = (e < vcnt) ? edges[(size_t)tile0 * arity + tid] : 0;
  }
  __syncthreads();
  if (tid < TILE) {
#pragma unroll
    for (int k = 0; k < 16; ++k) h0s[tid][k] = 0.f;
    if (tid < vcnt) {
      for (int o = 0; o < arity; ++o) {
        int id = idxs[tid * arity + o];
        h0s[tid][o * 2 + 0] = x[id * 2 + 0];
        h0s[tid][o * 2 + 1] = x[id * 2 + 1];
        h0s[tid][arity * 2 + o] = sigma;
      }
    }
  }
  __syncthreads();

  const int n0 = w * 64;

  f32x16 acc[2][2];    // [nb][eb], C: col(e)=l31, row(n)=(r&3)+8*(r>>2)+4*lh
#pragma unroll
  for (int nb = 0; nb < 2; ++nb)
#pragma unroll
    for (int eb = 0; eb < 2; ++eb)
#pragma unroll
      for (int r = 0; r < 16; ++r) acc[nb][eb][r] = 0.f;

  // ---- phase 1: z1^T = W1^T h0^T (split-bf16, single K=16 step) ----
  {
    short8 Hh[2], Hl[2];
#pragma unroll
    for (int eb = 0; eb < 2; ++eb) {
      const float* p = &h0s[eb * 32 + l31][lh * 8];
      f32x4 v0 = *(const f32x4*)p;
      f32x4 v1 = *(const f32x4*)(p + 4);
#pragma unroll
      for (int j = 0; j < 4; ++j) {
        unsigned short ha = f2bf(v0[j]);
        Hh[eb][j] = (short)ha;
        Hl[eb][j] = (short)f2bf(v0[j] - bf2f(ha));
        unsigned short hb_ = f2bf(v1[j]);
        Hh[eb][j + 4] = (short)hb_;
        Hl[eb][j + 4] = (short)f2bf(v1[j] - bf2f(hb_));
      }
    }
#pragma unroll
    for (int nb = 0; nb < 2; ++nb) {
      int nbg = w * 2 + nb;
      short8 A1h = *(const short8*)(W1hi + ((nbg * 64 + lane) << 3));
      short8 A1l = *(const short8*)(W1lo + ((nbg * 64 + lane) << 3));
#pragma unroll
      for (int eb = 0; eb < 2; ++eb) {
        acc[nb][eb] = __builtin_amdgcn_mfma_f32_32x32x16_bf16(A1h, Hh[eb], acc[nb][eb], 0, 0, 0);
        acc[nb][eb] = __builtin_amdgcn_mfma_f32_32x32x16_bf16(A1l, Hh[eb], acc[nb][eb], 0, 0, 0);
        acc[nb][eb] = __builtin_amdgcn_mfma_f32_32x32x16_bf16(A1h, Hl[eb], acc[nb][eb], 0, 0, 0);
      }
    }
  }
  // silu(z1) -> bufA[e][n], b64 per 4-reg group
#pragma unroll
  for (int nb = 0; nb < 2; ++nb) {
    int nbase = n0 + nb * 32;
#pragma unroll
    for (int eb = 0; eb < 2; ++eb) {
      int e = eb * 32 + l31;
      bool val = e < vcnt;
#pragma unroll
      for (int g = 0; g < 4; ++g) {
        int n4 = nbase + 8 * g + 4 * lh;
        f32x4 b1x = *(const f32x4*)&b1[n4];
        s16x4 pk;
#pragma unroll
        for (int r = 0; r < 4; ++r) {
          float z = acc[nb][eb][4 * g + r] + b1x[r];
          float s = fsig(z);
          pk[r] = (short)f2bf(val ? z * s : 0.f);
        }
        *(s16x4*)&bufA[bidx(e, n4)] = pk;
      }
    }
  }
  __syncthreads();

  // ---- phase 2: z2^T = W2^T h1^T, depth-1 af prefetch + setprio ----
#pragma unroll
  for (int nb = 0; nb < 2; ++nb)
#pragma unroll
    for (int eb = 0; eb < 2; ++eb)
#pragma unroll
      for (int r = 0; r < 16; ++r) acc[nb][eb][r] = 0.f;

  {
    short8 af_cur[2][2];   // [nb][t]
#pragma unroll
    for (int nb = 0; nb < 2; ++nb)
#pragma unroll
      for (int t = 0; t < 2; ++t)
        af_cur[nb][t] = *(const short8*)(Wf + ((((w * 2 + nb) * 32 + t) * 64 + lane) << 3));
#pragma unroll
    for (int c = 0; c < 16; ++c) {
      short8 af_nxt[2][2];
      int cn = (c + 1) & 15;
#pragma unroll
      for (int nb = 0; nb < 2; ++nb)
#pragma unroll
        for (int t = 0; t < 2; ++t)
          af_nxt[nb][t] = *(const short8*)(Wf + ((((w * 2 + nb) * 32 + cn * 2 + t) * 64 + lane) << 3));
      short8 hb[2][2];     // [eb][t]
#pragma unroll
      for (int eb = 0; eb < 2; ++eb)
#pragma unroll
        for (int t = 0; t < 2; ++t)
          hb[eb][t] = *(const short8*)&bufA[bidx(eb * 32 + l31, (c * 2 + t) * 16 + lh * 8)];
      __builtin_amdgcn_s_setprio(1);
#pragma unroll
      for (int t = 0; t < 2; ++t)
#pragma unroll
        for (int nb = 0; nb < 2; ++nb)
#pragma unroll
          for (int eb = 0; eb < 2; ++eb)
            acc[nb][eb] = __builtin_amdgcn_mfma_f32_32x32x16_bf16(af_cur[nb][t], hb[eb][t], acc[nb][eb], 0, 0, 0);
      __builtin_amdgcn_s_setprio(0);
#pragma unroll
      for (int nb = 0; nb < 2; ++nb)
#pragma unroll
        for (int t = 0; t < 2; ++t) af_cur[nb][t] = af_nxt[nb][t];
    }
  }

  // ---- epilogue fwd: energy + dz2 = w3*silu'(z2) ----
  float epart = 0.f;
#pragma unroll
  for (int nb = 0; nb < 2; ++nb) {
    int nbase = n0 + nb * 32;
#pragma unroll
    for (int eb = 0; eb < 2; ++eb) {
      bool val = (eb * 32 + l31) < vcnt;
#pragma unroll
      for (int g = 0; g < 4; ++g) {
        int n4 = nbase + 8 * g + 4 * lh;
        f32x4 b2x = *(const f32x4*)&b2[n4];
        f32x4 w3x = *(const f32x4*)&w3[n4];
#pragma unroll
        for (int r = 0; r < 4; ++r) {
          float z = acc[nb][eb][4 * g + r] + b2x[r];
          float s = fsig(z);
          float h2 = z * s;
          float sp = s * (1.f + z * (1.f - s));
          epart += val ? h2 * w3x[r] : 0.f;
          acc[nb][eb][4 * g + r] = val ? w3x[r] * sp : 0.f;
        }
      }
    }
  }

  __syncthreads();  // all reads of h1 done
#pragma unroll
  for (int nb = 0; nb < 2; ++nb) {
    int nbase = n0 + nb * 32;
#pragma unroll
    for (int eb = 0; eb < 2; ++eb) {
      int e = eb * 32 + l31;
#pragma unroll
      for (int g = 0; g < 4; ++g) {
        s16x4 pk;
#pragma unroll
        for (int r = 0; r < 4; ++r) pk[r] = (short)f2bf(acc[nb][eb][4 * g + r]);
        *(s16x4*)&bufA[bidx(e, nbase + 8 * g + 4 * lh)] = pk;
      }
    }
  }
#pragma unroll
  for (int off = 32; off > 0; off >>= 1) epart += __shfl_down(epart, off, 64);
  if (lane == 0) atomicAdd(&blockE, epart);
  __syncthreads();
  if (tid == 0) atomicAdd(out, blockE + (float)vcnt * b3p[0]);

  // ---- phase 3: dH1^T = W2 dz2^T, depth-1 af prefetch + setprio ----
#pragma unroll
  for (int nb = 0; nb < 2; ++nb)
#pragma unroll
    for (int eb = 0; eb < 2; ++eb)
#pragma unroll
      for (int r = 0; r < 16; ++r) acc[nb][eb][r] = 0.f;

  {
    short8 af_cur[2][2];
#pragma unroll
    for (int nb = 0; nb < 2; ++nb)
#pragma unroll
      for (int t = 0; t < 2; ++t)
        af_cur[nb][t] = *(const short8*)(Wb + ((((w * 2 + nb) * 32 + t) * 64 + lane) << 3));
#pragma unroll
    for (int c = 0; c < 16; ++c) {
      short8 af_nxt[2][2];
      int cn = (c + 1) & 15;
#pragma unroll
      for (int nb = 0; nb < 2; ++nb)
#pragma unroll
        for (int t = 0; t < 2; ++t)
          af_nxt[nb][t] = *(const short8*)(Wb + ((((w * 2 + nb) * 32 + cn * 2 + t) * 64 + lane) << 3));
      short8 hb[2][2];
#pragma unroll
      for (int eb = 0; eb < 2; ++eb)
#pragma unroll
        for (int t = 0; t < 2; ++t)
          hb[eb][t] = *(const short8*)&bufA[bidx(eb * 32 + l31, (c * 2 + t) * 16 + lh * 8)];
      __builtin_amdgcn_s_setprio(1);
#pragma unroll
      for (int t = 0; t < 2; ++t)
#pragma unroll
        for (int nb = 0; nb < 2; ++nb)
#pragma unroll
          for (int eb = 0; eb < 2; ++eb)
            acc[nb][eb] = __builtin_amdgcn_mfma_f32_32x32x16_bf16(af_cur[nb][t], hb[eb][t], acc[nb][eb], 0, 0, 0);
      __builtin_amdgcn_s_setprio(0);
#pragma unroll
      for (int nb = 0; nb < 2; ++nb)
#pragma unroll
        for (int t = 0; t < 2; ++t) af_cur[nb][t] = af_nxt[nb][t];
    }
  }

  // ---- phase 4: dz1 = dH1 * silu'(z1); z1 via bf16 re-MFMA (Hh rebuilt) ----
#pragma unroll
  for (int nb = 0; nb < 2; ++nb) {
    int nbg = w * 2 + nb;
    int nbase = n0 + nb * 32;
    short8 A1h = *(const short8*)(W1hi + ((nbg * 64 + lane) << 3));
#pragma unroll
    for (int eb = 0; eb < 2; ++eb) {
      short8 Hh;
      {
        const float* p = &h0s[eb * 32 + l31][lh * 8];
        f32x4 v0 = *(const f32x4*)p;
        f32x4 v1 = *(const f32x4*)(p + 4);
#pragma unroll
        for (int j = 0; j < 4; ++j) {
          Hh[j] = (short)f2bf(v0[j]);
          Hh[j + 4] = (short)f2bf(v1[j]);
        }
      }
      f32x16 zacc;
#pragma unroll
      for (int r = 0; r < 16; ++r) zacc[r] = 0.f;
      zacc = __builtin_amdgcn_mfma_f32_32x32x16_bf16(A1h, Hh, zacc, 0, 0, 0);
#pragma unroll
      for (int g = 0; g < 4; ++g) {
        f32x4 b1x = *(const f32x4*)&b1[nbase + 8 * g + 4 * lh];
#pragma unroll
        for (int r = 0; r < 4; ++r) {
          float z = zacc[4 * g + r] + b1x[r];
          float s = fsig(z);
          float sp = s * (1.f + z * (1.f - s));
          acc[nb][eb][4 * g + r] *= sp;
        }
      }
    }
  }

  // ---- phase 5 (fused, in-register): dh0 partial over own n-cols ----
  // dz1 C-layout -> phase-5 B-fragments via bf16 pack + v_permlane32_swap:
  // reader (l31,lh) needs k-offsets sub+8*lh+j; j=0..3 live in lh'=0 lanes,
  // j=4..7 in lh'=1 lanes, both at reg-group g=sub/8+lh. swap(p(g1),p(g0))
  // yields words{0,1}=vsrc' and {2,3}=vdst' correct for ALL lanes.
  {
    f32x16 pacc[2];
#pragma unroll
    for (int eb = 0; eb < 2; ++eb)
#pragma unroll
      for (int r = 0; r < 16; ++r) pacc[eb][r] = 0.f;
#pragma unroll
    for (int nb = 0; nb < 2; ++nb) {
#pragma unroll
      for (int eb = 0; eb < 2; ++eb) {
        unsigned plo[4], phi[4];
#pragma unroll
        for (int g = 0; g < 4; ++g) {
          plo[g] = (unsigned)f2bf(acc[nb][eb][4 * g + 0]) |
                   ((unsigned)f2bf(acc[nb][eb][4 * g + 1]) << 16);
          phi[g] = (unsigned)f2bf(acc[nb][eb][4 * g + 2]) |
                   ((unsigned)f2bf(acc[nb][eb][4 * g + 3]) << 16);
        }
#pragma unroll
        for (int sb = 0; sb < 2; ++sb) {
          unsigned a_lo = plo[2 * sb + 1], b_lo = plo[2 * sb];
          unsigned a_hi = phi[2 * sb + 1], b_hi = phi[2 * sb];
          asm volatile("v_permlane32_swap_b32 %0, %1" : "+v"(a_lo), "+v"(b_lo));
          asm volatile("v_permlane32_swap_b32 %0, %1" : "+v"(a_hi), "+v"(b_hi));
          short8 bfrag;
          bfrag[0] = (short)(b_lo & 0xffff); bfrag[1] = (short)(b_lo >> 16);
          bfrag[2] = (short)(b_hi & 0xffff); bfrag[3] = (short)(b_hi >> 16);
          bfrag[4] = (short)(a_lo & 0xffff); bfrag[5] = (short)(a_lo >> 16);
          bfrag[6] = (short)(a_hi & 0xffff); bfrag[7] = (short)(a_hi >> 16);
          int kc = w * 4 + nb * 2 + sb;
          short8 a5 = *(const short8*)(W1p5 + ((kc * 64 + lane) << 3));
          pacc[eb] = __builtin_amdgcn_mfma_f32_32x32x16_bf16(a5, bfrag, pacc[eb], 0, 0, 0);
        }
      }
    }
#pragma unroll
    for (int eb = 0; eb < 2; ++eb)
#pragma unroll
      for (int r = 0; r < 4; ++r) {
        int g = r + 4 * lh;
        if (g < GD) atomicAdd(&dh0sT[g][eb * 32 + l31], pacc[eb][r]);
      }
  }
  __syncthreads();

  // ---- scatter grads ----
  {
    int e = tid & 63, g = tid >> 6;     // 512 threads = 64 edges x 8 comps
    if (e < vcnt && g < GD) {
      int obj = g >> 1, d = g & 1;
      atomicAdd(&out[1 + idxs[e * arity + obj] * 2 + d], dh0sT[g][e]);
    }
  }
}

extern "C" void kernel_launch(void* const* d_in, const int* in_sizes, int n_in,
                              void* d_out, int out_size, void* d_ws, size_t ws_size,
                              hipStream_t stream) {
  const float* x    = (const float*)d_in[0];
  const float* sig  = (const float*)d_in[1];
  const int*   ep   = (const int*)d_in[2];
  const int*   et   = (const int*)d_in[3];
  const float* pW1  = (const float*)d_in[4];
  const float* pb1  = (const float*)d_in[5];
  const float* pW2  = (const float*)d_in[6];
  const float* pb2  = (const float*)d_in[7];
  const float* pW3  = (const float*)d_in[8];
  const float* pb3  = (const float*)d_in[9];
  const float* tW1  = (const float*)d_in[10];
  const float* tb1  = (const float*)d_in[11];
  const float* tW2  = (const float*)d_in[12];
  const float* tb2  = (const float*)d_in[13];
  const float* tW3  = (const float*)d_in[14];
  const float* tb3  = (const float*)d_in[15];
  const int E2 = in_sizes[2] / 2;
  const int E3 = in_sizes[3] / 3;
  float* out = (float*)d_out;

  unsigned short* pWf = (unsigned short*)d_ws;
  unsigned short* pWb = pWf + HDIM * HDIM;
  unsigned short* tWf = pWb + HDIM * HDIM;
  unsigned short* tWb = tWf + HDIM * HDIM;
  unsigned short* pW1hi = tWb + HDIM * HDIM;
  unsigned short* pW1lo = pW1hi + 16 * 64 * 8;
  unsigned short* pW1p5 = pW1lo + 16 * 64 * 8;
  unsigned short* tW1hi = pW1p5 + 32 * 64 * 8;
  unsigned short* tW1lo = tW1hi + 16 * 64 * 8;
  unsigned short* tW1p5 = tW1lo + 16 * 64 * 8;

  const int nb2 = (E2 + TILE - 1) / TILE;
  const int nb3 = (E3 + TILE - 1) / TILE;

  hipMemsetAsync(d_out, 0, (size_t)out_size * sizeof(float), stream);
  prep_weights<<<(HDIM * HDIM + 255) / 256, 256, 0, stream>>>(pW2, tW2, pWf, pWb, tWf, tWb);
  prep_w1<<<(16 * 64 * 8 + 32 * 64 * 8 + 255) / 256, 256, 0, stream>>>(pW1, 6, 4, pW1hi, pW1lo, pW1p5);
  prep_w1<<<(16 * 64 * 8 + 32 * 64 * 8 + 255) / 256, 256, 0, stream>>>(tW1, 9, 6, tW1hi, tW1lo, tW1p5);
  energy_kernel<<<nb2 + nb3, TPB, 0, stream>>>(
      x, sig, ep, et, E2, E3, nb2,
      pW1hi, pW1lo, pW1p5, tW1hi, tW1lo, tW1p5, pb1, tb1,
      pWf, pWb, tWf, tWb, pb2, tb2, pW3, tW3, pb3, tb3, out);
}